// Round 3
// baseline (184.090 us; speedup 1.0000x reference)
//
#include <hip/hip_runtime.h>
#include <hip/hip_bf16.h>
#include <math.h>

#define D_MODEL 1024
#define N_HEADS 16
#define N_KV 4
#define HEAD_DIM 64
#define SEQ 2048
#define BATCH 2
#define M_TOK (BATCH * SEQ)

typedef unsigned int u32;
typedef unsigned short u16;
typedef __attribute__((ext_vector_type(8))) short short8;
typedef __attribute__((ext_vector_type(4))) float f32x4;
typedef __attribute__((ext_vector_type(16))) float f32x16;

#define AS1 __attribute__((address_space(1)))
#define AS3 __attribute__((address_space(3)))

__device__ __forceinline__ u16 f2bf(float f) {
  union { __hip_bfloat16 h; u16 u; } c; c.h = __float2bfloat16(f); return c.u;
}
__device__ __forceinline__ u32 pk2(float a, float b) {
  return (u32)f2bf(a) | ((u32)f2bf(b) << 16);
}
__device__ __forceinline__ u32 cvtpk(float lo, float hi) {
  u32 r; asm("v_cvt_pk_bf16_f32 %0, %1, %2" : "=v"(r) : "v"(lo), "v"(hi)); return r;
}
__device__ __forceinline__ void plswap(u32& a, u32& b) {
  asm volatile("v_permlane32_swap_b32 %0, %1" : "+v"(a), "+v"(b));
}
__device__ __forceinline__ float exp2fast(float x) { return __builtin_amdgcn_exp2f(x); }
__device__ __forceinline__ float rcpfast(float x) { return __builtin_amdgcn_rcpf(x); }

// ---------------------------------------------------------------------------
// prep: wq/wk/wv transpose-casts in one launch.  wT[n][k] = bf16(w[k][n]),
// wT row stride 1024.  blocks: [0,1024) wq, [1024,1280) wk, [1280,1536) wv.
// ---------------------------------------------------------------------------
__global__ __launch_bounds__(256) void prep_kernel(const float* __restrict__ wq,
                                                   const float* __restrict__ wk,
                                                   const float* __restrict__ wv,
                                                   u16* __restrict__ wT) {
  __shared__ float t[32][33];
  int bx = blockIdx.x;
  const float* src; u16* dst; int N, ntm, nts;
  if (bx < 1024)      { src = wq; dst = wT;                 N = 1024; ntm = 31; nts = 5; }
  else if (bx < 1280) { bx -= 1024; src = wk; dst = wT + (1024 << 10); N = 256; ntm = 7; nts = 3; }
  else                { bx -= 1280; src = wv; dst = wT + (1280 << 10); N = 256; ntm = 7; nts = 3; }
  const int n0 = (bx & ntm) << 5, k0 = (bx >> nts) << 5;
  const int x = threadIdx.x & 31, y = threadIdx.x >> 5;
#pragma unroll
  for (int i = 0; i < 4; ++i) {
    int r = y + (i << 3);
    t[r][x] = src[(size_t)(k0 + r) * N + n0 + x];
  }
  __syncthreads();
#pragma unroll
  for (int i = 0; i < 4; ++i) {
    int r = y + (i << 3);
    dst[(size_t)(n0 + r) * 1024 + k0 + x] = f2bf(t[x][r]);
  }
}

// ---------------------------------------------------------------------------
// bf16 MFMA GEMM: C[M][N] f32 = A[M][K] @ B^T[N][K].  128x128 tile, BK=32,
// 256 thr (4 waves, 64x64 quadrant each), double-buffered LDS.
// AF32: A is f32 (reg-staged + cast); else bf16 via global_load_lds.
// ---------------------------------------------------------------------------
template<bool AF32>
__global__ __launch_bounds__(256, 2) void gemm_kernel(const void* __restrict__ Ap,
                                                      const u16* __restrict__ BT,
                                                      float* __restrict__ C,
                                                      int K, int ldc) {
  __shared__ uint4 As[2][512];
  __shared__ uint4 Bs[2][512];
  const int tid = threadIdx.x;
  const int w = tid >> 6, l = tid & 63;
  const int wr = w >> 1, wc = w & 1;
  const int m0 = blockIdx.y << 7, n0 = blockIdx.x << 7;

  f32x4 acc[4][4];
#pragma unroll
  for (int m = 0; m < 4; ++m)
#pragma unroll
    for (int n = 0; n < 4; ++n)
#pragma unroll
      for (int j = 0; j < 4; ++j) acc[m][n][j] = 0.f;

  auto stageAB = [&](int buf, int k0) {
    if (AF32) {
      const float* Af = (const float*)Ap + (size_t)m0 * K + k0;
#pragma unroll
      for (int i = 0; i < 2; ++i) {
        int c = tid + (i << 8);
        int row = c >> 2, q = c & 3;
        const float* g = Af + (size_t)row * K + (q << 3);
        float4 f0 = *(const float4*)g;
        float4 f1 = *(const float4*)(g + 4);
        uint4 u;
        u.x = pk2(f0.x, f0.y); u.y = pk2(f0.z, f0.w);
        u.z = pk2(f1.x, f1.y); u.w = pk2(f1.z, f1.w);
        *(uint4*)((char*)As[buf] + (row << 6) + (q << 4)) = u;
      }
    } else {
      const u16* Ab = (const u16*)Ap + (size_t)m0 * K + k0;
#pragma unroll
      for (int r = 0; r < 2; ++r) {
        int i = ((tid >> 6) << 1) + r;
        int row = (i << 4) + ((tid & 63) >> 2);
        const u16* g = Ab + (size_t)row * K + ((tid & 3) << 3);
        __builtin_amdgcn_global_load_lds((const AS1 void*)g,
            (AS3 void*)((char*)As[buf] + (i << 10)), 16, 0, 0);
      }
    }
    const u16* Bb = BT + (size_t)n0 * K + k0;
#pragma unroll
    for (int r = 0; r < 2; ++r) {
      int i = ((tid >> 6) << 1) + r;
      int row = (i << 4) + ((tid & 63) >> 2);
      const u16* g = Bb + (size_t)row * K + ((tid & 3) << 3);
      __builtin_amdgcn_global_load_lds((const AS1 void*)g,
          (AS3 void*)((char*)Bs[buf] + (i << 10)), 16, 0, 0);
    }
  };

  const int KT = K >> 5;
  stageAB(0, 0);
#pragma unroll 1
  for (int kt = 0; kt < KT; ++kt) {
    __syncthreads();
    if (kt + 1 < KT) stageAB((kt + 1) & 1, (kt + 1) << 5);
    const char* Ab = (const char*)As[kt & 1];
    const char* Bb = (const char*)Bs[kt & 1];
    short8 af[4], bf[4];
#pragma unroll
    for (int m = 0; m < 4; ++m)
      af[m] = *(const short8*)(Ab + ((wr * 64 + m * 16 + (l & 15)) << 6) + ((l >> 4) << 4));
#pragma unroll
    for (int n = 0; n < 4; ++n)
      bf[n] = *(const short8*)(Bb + ((wc * 64 + n * 16 + (l & 15)) << 6) + ((l >> 4) << 4));
    __builtin_amdgcn_s_setprio(1);
#pragma unroll
    for (int m = 0; m < 4; ++m)
#pragma unroll
      for (int n = 0; n < 4; ++n)
        acc[m][n] = __builtin_amdgcn_mfma_f32_16x16x32_bf16(af[m], bf[n], acc[m][n], 0, 0, 0);
    __builtin_amdgcn_s_setprio(0);
  }

#pragma unroll
  for (int m = 0; m < 4; ++m) {
    int row0 = m0 + wr * 64 + m * 16 + ((l >> 4) << 2);
#pragma unroll
    for (int n = 0; n < 4; ++n) {
      int col = n0 + wc * 64 + n * 16 + (l & 15);
#pragma unroll
      for (int j = 0; j < 4; ++j)
        C[(size_t)(row0 + j) * ldc + col] = acc[m][n][j];
    }
  }
}

// ---------------------------------------------------------------------------
// post: normrope ([0,4096)) + V transpose-cast ([4096,4352)) in one launch.
// ---------------------------------------------------------------------------
__global__ __launch_bounds__(256) void post_kernel(const float* __restrict__ qkv,
                                                   u16* __restrict__ Qbf,
                                                   u16* __restrict__ Kbf,
                                                   u16* __restrict__ Vt) {
  __shared__ float tt[64][65];
  const int bid = blockIdx.x;
  if (bid < 4096) {
    // RMSNorm + RoPE; Qbf [b][h][s][64] (x 1/(8*CAP)), Kbf [b][hkv][s][64]
    const int t = bid;
    const int pos = t & 2047, b = t >> 11;
    const int wv = threadIdx.x >> 6, lane = threadIdx.x & 63;
    const int fi = lane & 31;
    const float invf = 1.0f / powf(10000.0f, (float)fi * (1.0f / 32.0f));
    float sn, cs; sincosf((float)pos * invf, &sn, &cs);
    const float* row = qkv + (size_t)t * 1536;
#pragma unroll
    for (int hh = 0; hh < 4; ++hh) {
      const int h = wv * 4 + hh;
      float val = row[h * 64 + lane];
      float ss = val * val;
#pragma unroll
      for (int off = 32; off; off >>= 1) ss += __shfl_xor(ss, off);
      val *= rsqrtf(ss * (1.f / 64.f) + 1e-5f);
      float partner = __shfl_xor(val, 32);
      float o = (lane < 32) ? (val * cs - partner * sn) : (val * cs + partner * sn);
      Qbf[((size_t)(b * 16 + h) * 2048 + pos) * 64 + lane] = f2bf(o * 0.0025f);
    }
    {
      float val = row[1024 + wv * 64 + lane];
      float ss = val * val;
#pragma unroll
      for (int off = 32; off; off >>= 1) ss += __shfl_xor(ss, off);
      val *= rsqrtf(ss * (1.f / 64.f) + 1e-5f);
      float partner = __shfl_xor(val, 32);
      float o = (lane < 32) ? (val * cs - partner * sn) : (val * cs + partner * sn);
      Kbf[((size_t)(b * 4 + wv) * 2048 + pos) * 64 + lane] = f2bf(o);
    }
    return;
  }
  // V transpose: Vt[b][hkv][d][s]
  const int t2 = bid - 4096;
  const int bkv = t2 >> 5;
  const int s0 = (t2 & 31) << 6;
  const int r = threadIdx.x >> 4, c4 = (threadIdx.x & 15) << 2;
#pragma unroll
  for (int i = 0; i < 4; ++i) {
    int row = r + (i << 4);
    const float* g = qkv + (size_t)(((bkv >> 2) * 2048 + s0 + row)) * 1536
                   + 1280 + ((bkv & 3) << 6) + c4;
    float4 v = *(const float4*)g;
    tt[row][c4] = v.x; tt[row][c4 + 1] = v.y; tt[row][c4 + 2] = v.z; tt[row][c4 + 3] = v.w;
  }
  __syncthreads();
#pragma unroll
  for (int i = 0; i < 4; ++i) {
    int d = r + (i << 4);
    uint2 u;
    u.x = pk2(tt[c4][d], tt[c4 + 1][d]);
    u.y = pk2(tt[c4 + 2][d], tt[c4 + 3][d]);
    *(uint2*)(Vt + (size_t)(bkv * 64 + d) * 2048 + s0 + c4) = u;
  }
}

// ---------------------------------------------------------------------------
// Flash attention, fixed-max softmax (softcap bounds scores to |sc|<8):
// p = exp(sc - 8), no running max / rescale.  Block = 128 thr (2 waves x 32
// q-rows), QBLK=64, KVBLK=64 double-buffered, async reg-staged (T14), T5
// setprio around MFMA.  Blocks >= 1024 do the wo transpose-cast instead.
// ---------------------------------------------------------------------------
__device__ __forceinline__ short8 rdfrag(const uint4* lds, int row, int cb) {
  int byte = ((row << 7) + cb) ^ ((row & 7) << 4);
  return *(const short8*)((const char*)lds + byte);
}

__global__ __launch_bounds__(128, 3) void attn_kernel(const u16* __restrict__ Qbf,
                                                      const u16* __restrict__ Kbf,
                                                      const u16* __restrict__ Vt,
                                                      u16* __restrict__ ybf,
                                                      const float* __restrict__ wo,
                                                      u16* __restrict__ woT) {
  __shared__ uint4 KV[4][512];         // K0 V0 K1 V1, 64x64 bf16, XOR-swizzled
  const int tid = threadIdx.x;

  if (blockIdx.x >= 1024) {            // ---- wo transpose-cast tail blocks ----
    float* tt = (float*)KV;            // 32x33 f32 tile
    const int t = blockIdx.x - 1024;
    const int n0 = (t & 31) << 5, k0 = (t >> 5) << 5;
    const int x = tid & 31, y = tid >> 5;          // y: 0..3
#pragma unroll
    for (int i = 0; i < 8; ++i) {
      int r = y + (i << 2);
      tt[r * 33 + x] = wo[(size_t)(k0 + r) * 1024 + n0 + x];
    }
    __syncthreads();
#pragma unroll
    for (int i = 0; i < 8; ++i) {
      int r = y + (i << 2);
      woT[(size_t)(n0 + r) * 1024 + k0 + x] = f2bf(tt[x * 33 + r]);
    }
    return;
  }

  const int bh = blockIdx.x & 31;
  const int qt = 31 - (blockIdx.x >> 5);   // heavy q-tiles dispatch first
  const int q0 = qt << 6;
  const int w = tid >> 6, l = tid & 63;
  const int ql = l & 31, myh = l >> 5;
  const int b = bh >> 4, h = bh & 15, hkv = h >> 2;
  const int qg = q0 + (w << 5) + ql;

  const u16* Kg = Kbf + (((size_t)(b * 4 + hkv)) << 11) * 64;
  const u16* Vg = Vt + (((size_t)(b * 4 + hkv)) << 6) * 2048;

  short8 bq[4];
  {
    const u16* Qg = Qbf + ((size_t)((b * 16 + h) * 2048 + qg)) * 64 + myh * 8;
    bq[0] = *(const short8*)(Qg);
    bq[1] = *(const short8*)(Qg + 16);
    bq[2] = *(const short8*)(Qg + 32);
    bq[3] = *(const short8*)(Qg + 48);
  }

  f32x16 o0, o1;
#pragma unroll
  for (int i = 0; i < 16; ++i) { o0[i] = 0.f; o1[i] = 0.f; }
  float l_run = 0.f;

  const int KT = qt + 1;
  uint4 rK[4], rV[4];

  auto ldKV = [&](int kt) {
    const u16* gk = Kg + ((size_t)(kt << 6)) * 64;
    const u16* gv = Vg + (kt << 6);
#pragma unroll
    for (int i = 0; i < 4; ++i) {
      int c = tid + (i << 7);
      int row = c >> 3, off = c & 7;
      rK[i] = *(const uint4*)(gk + row * 64 + (off << 3));
      rV[i] = *(const uint4*)(gv + (size_t)row * 2048 + (off << 3));
    }
  };
  auto wrKV = [&](int buf) {
#pragma unroll
    for (int i = 0; i < 4; ++i) {
      int c = tid + (i << 7);
      int row = c >> 3, off = c & 7;
      int byte = ((row << 7) + (off << 4)) ^ ((row & 7) << 4);
      *(uint4*)((char*)KV[buf << 1] + byte) = rK[i];
      *(uint4*)((char*)KV[(buf << 1) + 1] + byte) = rV[i];
    }
  };

  ldKV(0);
  wrKV(0);
  if (KT > 1) ldKV(1);

  const float TL2E = 2.8853900817779268f;   // 2*log2(e)
  const float MC1 = 144.26950408889634f;    // 100*log2(e)
  const float MC0 = 60.59319171733646f;     // 42*log2(e)  (m = 8 folded)

#pragma unroll 1
  for (int kt = 0; kt < KT; ++kt) {
    const int k0 = kt << 6;
    const int buf = kt & 1;
    __syncthreads();
    if (kt + 1 < KT) {
      wrKV(buf ^ 1);                   // write tile kt+1 (loads have landed)
      if (kt + 2 < KT) ldKV(kt + 2);   // issue loads for tile kt+2
    }
    const bool full = (k0 + 63 <= q0 + (w << 5));
    const uint4* Kl = KV[buf << 1];
    const uint4* Vl = KV[(buf << 1) + 1];

    f32x16 s0, s1;                     // scores^T: col = q(l&31), row = k
#pragma unroll
    for (int i = 0; i < 16; ++i) { s0[i] = 0.f; s1[i] = 0.f; }
    __builtin_amdgcn_s_setprio(1);
#pragma unroll
    for (int c = 0; c < 4; ++c) {
      short8 ak = rdfrag(Kl, ql, (c << 5) + (myh << 4));
      s0 = __builtin_amdgcn_mfma_f32_32x32x16_bf16(ak, bq[c], s0, 0, 0, 0);
    }
#pragma unroll
    for (int c = 0; c < 4; ++c) {
      short8 ak = rdfrag(Kl, 32 + ql, (c << 5) + (myh << 4));
      s1 = __builtin_amdgcn_mfma_f32_32x32x16_bf16(ak, bq[c], s1, 0, 0, 0);
    }
    __builtin_amdgcn_s_setprio(0);

    // softcap + exp with fixed max: p = exp2((50 - 100/(e^{2x}+1) - 8)*log2e)
    float lsum = 0.f;
    if (full) {
#pragma unroll
      for (int i = 0; i < 16; ++i) {
        float r = rcpfast(exp2fast(s0[i] * TL2E) + 1.f);
        float p = exp2fast(fmaf(-MC1, r, MC0));
        s0[i] = p; lsum += p;
      }
#pragma unroll
      for (int i = 0; i < 16; ++i) {
        float r = rcpfast(exp2fast(s1[i] * TL2E) + 1.f);
        float p = exp2fast(fmaf(-MC1, r, MC0));
        s1[i] = p; lsum += p;
      }
    } else {
#pragma unroll
      for (int i = 0; i < 16; ++i) {
        int kk = k0 + (i & 3) + ((i >> 2) << 3) + (myh << 2);
        float r = rcpfast(exp2fast(s0[i] * TL2E) + 1.f);
        float p = exp2fast(fmaf(-MC1, r, MC0));
        p = (kk <= qg) ? p : 0.f;
        s0[i] = p; lsum += p;
      }
#pragma unroll
      for (int i = 0; i < 16; ++i) {
        int kk = k0 + 32 + (i & 3) + ((i >> 2) << 3) + (myh << 2);
        float r = rcpfast(exp2fast(s1[i] * TL2E) + 1.f);
        float p = exp2fast(fmaf(-MC1, r, MC0));
        p = (kk <= qg) ? p : 0.f;
        s1[i] = p; lsum += p;
      }
    }
    l_run += lsum;

    // P -> bf16 B-frags: pa[c][j] = P[q = l&31][k = c*16 + myh*8 + j]
    short8 pa[4];
#pragma unroll
    for (int c = 0; c < 4; ++c) {
      const f32x16& P = (c < 2) ? s0 : s1;
      const int rb = (c & 1) << 3;
      u32 A = cvtpk(P[rb + 0], P[rb + 1]);
      u32 Cw = cvtpk(P[rb + 2], P[rb + 3]);
      u32 B = cvtpk(P[rb + 4], P[rb + 5]);
      u32 D = cvtpk(P[rb + 6], P[rb + 7]);
      plswap(A, B); plswap(Cw, D);
      union { u32 u[4]; short8 s; } pw;
      pw.u[0] = A; pw.u[1] = Cw; pw.u[2] = B; pw.u[3] = D;
      pa[c] = pw.s;
    }

    // O^T += V^T * P^T
    __builtin_amdgcn_s_setprio(1);
#pragma unroll
    for (int c = 0; c < 4; ++c) {
      short8 av = rdfrag(Vl, ql, (c << 5) + (myh << 4));
      o0 = __builtin_amdgcn_mfma_f32_32x32x16_bf16(av, pa[c], o0, 0, 0, 0);
    }
#pragma unroll
    for (int c = 0; c < 4; ++c) {
      short8 av = rdfrag(Vl, 32 + ql, (c << 5) + (myh << 4));
      o1 = __builtin_amdgcn_mfma_f32_32x32x16_bf16(av, pa[c], o1, 0, 0, 0);
    }
    __builtin_amdgcn_s_setprio(0);
  }

  float lr = l_run + __shfl_xor(l_run, 32);
  float rl = rcpfast(lr);
  u16* yr = ybf + ((size_t)(b * 2048 + qg)) * 1024 + h * 64;
#pragma unroll
  for (int i = 0; i < 16; i += 2) {
    int dof = (i & 3) + ((i >> 2) << 3) + (myh << 2);
    *(u32*)(yr + dof) = cvtpk(o0[i] * rl, o0[i + 1] * rl);
    *(u32*)(yr + 32 + dof) = cvtpk(o1[i] * rl, o1[i + 1] * rl);
  }
}

// ---------------------------------------------------------------------------
extern "C" void kernel_launch(void* const* d_in, const int* in_sizes, int n_in,
                              void* d_out, int out_size, void* d_ws, size_t ws_size,
                              hipStream_t stream) {
  (void)in_sizes; (void)n_in; (void)out_size; (void)ws_size;
  const float* x  = (const float*)d_in[0];
  const float* wq = (const float*)d_in[1];
  const float* wk = (const float*)d_in[2];
  const float* wv = (const float*)d_in[3];
  const float* wo = (const float*)d_in[4];
  float* out = (float*)d_out;

  char* ws = (char*)d_ws;
  float* qkv = (float*)ws;               // [0, 24M) f32, dead after post
  u16* ybf = (u16*)ws;                   // [0, 8M)  alias (attn output)
  u16* woT = (u16*)(ws + (8u << 20));    // [8, 10M) alias (written in attn launch)
  u16* wT  = (u16*)(ws + (24u << 20));   // [24, 27M)
  u16* Qbf = (u16*)(ws + (27u << 20));   // [27, 35M)
  u16* Kbf = (u16*)(ws + (35u << 20));   // [35, 37M)
  u16* Vt  = (u16*)(ws + (37u << 20));   // [37, 39M)

  prep_kernel<<<dim3(1536), 256, 0, stream>>>(wq, wk, wv, wT);
  gemm_kernel<true><<<dim3(12, 32), 256, 0, stream>>>(x, wT, qkv, 1024, 1536);
  post_kernel<<<dim3(4352), 256, 0, stream>>>(qkv, Qbf, Kbf, Vt);
  attn_kernel<<<dim3(2048), 128, 0, stream>>>(Qbf, Kbf, Vt, ybf, wo, woT);
  gemm_kernel<false><<<dim3(8, 32), 256, 0, stream>>>(ybf, woT, out, 1024, 1024);
}

// Round 4
// 136.377 us; speedup vs baseline: 1.3499x; 1.3499x over previous
//
#include <hip/hip_runtime.h>
#include <hip/hip_bf16.h>
#include <math.h>

#define D_MODEL 1024
#define N_HEADS 16
#define N_KV 4
#define HEAD_DIM 64
#define SEQ 2048
#define BATCH 2
#define M_TOK (BATCH * SEQ)

typedef unsigned int u32;
typedef unsigned short u16;
typedef __attribute__((ext_vector_type(8))) short short8;
typedef __attribute__((ext_vector_type(4))) float f32x4;
typedef __attribute__((ext_vector_type(16))) float f32x16;

#define AS1 __attribute__((address_space(1)))
#define AS3 __attribute__((address_space(3)))

__device__ __forceinline__ u16 f2bf(float f) {
  union { __hip_bfloat16 h; u16 u; } c; c.h = __float2bfloat16(f); return c.u;
}
__device__ __forceinline__ u32 pk2(float a, float b) {
  return (u32)f2bf(a) | ((u32)f2bf(b) << 16);
}
__device__ __forceinline__ u32 cvtpk(float lo, float hi) {
  u32 r; asm("v_cvt_pk_bf16_f32 %0, %1, %2" : "=v"(r) : "v"(lo), "v"(hi)); return r;
}
__device__ __forceinline__ void plswap(u32& a, u32& b) {
  asm volatile("v_permlane32_swap_b32 %0, %1" : "+v"(a), "+v"(b));
}
__device__ __forceinline__ float exp2fast(float x) { return __builtin_amdgcn_exp2f(x); }
__device__ __forceinline__ float rcpfast(float x) { return __builtin_amdgcn_rcpf(x); }

// ---------------------------------------------------------------------------
// prep: wq/wk/wv transpose-casts in one launch.  wT[n][k] = bf16(w[k][n]),
// wT row stride 1024.  blocks: [0,1024) wq, [1024,1280) wk, [1280,1536) wv.
// ---------------------------------------------------------------------------
__global__ __launch_bounds__(256) void prep_kernel(const float* __restrict__ wq,
                                                   const float* __restrict__ wk,
                                                   const float* __restrict__ wv,
                                                   u16* __restrict__ wT) {
  __shared__ float t[32][33];
  int bx = blockIdx.x;
  const float* src; u16* dst; int N, ntm, nts;
  if (bx < 1024)      { src = wq; dst = wT;                 N = 1024; ntm = 31; nts = 5; }
  else if (bx < 1280) { bx -= 1024; src = wk; dst = wT + (1024 << 10); N = 256; ntm = 7; nts = 3; }
  else                { bx -= 1280; src = wv; dst = wT + (1280 << 10); N = 256; ntm = 7; nts = 3; }
  const int n0 = (bx & ntm) << 5, k0 = (bx >> nts) << 5;
  const int x = threadIdx.x & 31, y = threadIdx.x >> 5;
#pragma unroll
  for (int i = 0; i < 4; ++i) {
    int r = y + (i << 3);
    t[r][x] = src[(size_t)(k0 + r) * N + n0 + x];
  }
  __syncthreads();
#pragma unroll
  for (int i = 0; i < 4; ++i) {
    int r = y + (i << 3);
    dst[(size_t)(n0 + r) * 1024 + k0 + x] = f2bf(t[x][r]);
  }
}

// ---------------------------------------------------------------------------
// bf16 MFMA GEMM: C[M][N] f32 = A[M][K] @ B^T[N][K].  128x128 tile, BK=32,
// 256 thr (4 waves, 64x64 quadrant each), double-buffered LDS.
// AF32: A is f32 (reg-staged + cast); else bf16 via global_load_lds.
// ---------------------------------------------------------------------------
template<bool AF32>
__global__ __launch_bounds__(256, 2) void gemm_kernel(const void* __restrict__ Ap,
                                                      const u16* __restrict__ BT,
                                                      float* __restrict__ C,
                                                      int K, int ldc) {
  __shared__ uint4 As[2][512];
  __shared__ uint4 Bs[2][512];
  const int tid = threadIdx.x;
  const int w = tid >> 6, l = tid & 63;
  const int wr = w >> 1, wc = w & 1;
  const int m0 = blockIdx.y << 7, n0 = blockIdx.x << 7;

  f32x4 acc[4][4];
#pragma unroll
  for (int m = 0; m < 4; ++m)
#pragma unroll
    for (int n = 0; n < 4; ++n)
#pragma unroll
      for (int j = 0; j < 4; ++j) acc[m][n][j] = 0.f;

  auto stageAB = [&](int buf, int k0) {
    if (AF32) {
      const float* Af = (const float*)Ap + (size_t)m0 * K + k0;
#pragma unroll
      for (int i = 0; i < 2; ++i) {
        int c = tid + (i << 8);
        int row = c >> 2, q = c & 3;
        const float* g = Af + (size_t)row * K + (q << 3);
        float4 f0 = *(const float4*)g;
        float4 f1 = *(const float4*)(g + 4);
        uint4 u;
        u.x = pk2(f0.x, f0.y); u.y = pk2(f0.z, f0.w);
        u.z = pk2(f1.x, f1.y); u.w = pk2(f1.z, f1.w);
        *(uint4*)((char*)As[buf] + (row << 6) + (q << 4)) = u;
      }
    } else {
      const u16* Ab = (const u16*)Ap + (size_t)m0 * K + k0;
#pragma unroll
      for (int r = 0; r < 2; ++r) {
        int i = ((tid >> 6) << 1) + r;
        int row = (i << 4) + ((tid & 63) >> 2);
        const u16* g = Ab + (size_t)row * K + ((tid & 3) << 3);
        __builtin_amdgcn_global_load_lds((const AS1 void*)g,
            (AS3 void*)((char*)As[buf] + (i << 10)), 16, 0, 0);
      }
    }
    const u16* Bb = BT + (size_t)n0 * K + k0;
#pragma unroll
    for (int r = 0; r < 2; ++r) {
      int i = ((tid >> 6) << 1) + r;
      int row = (i << 4) + ((tid & 63) >> 2);
      const u16* g = Bb + (size_t)row * K + ((tid & 3) << 3);
      __builtin_amdgcn_global_load_lds((const AS1 void*)g,
          (AS3 void*)((char*)Bs[buf] + (i << 10)), 16, 0, 0);
    }
  };

  const int KT = K >> 5;
  stageAB(0, 0);
#pragma unroll 1
  for (int kt = 0; kt < KT; ++kt) {
    __syncthreads();
    if (kt + 1 < KT) stageAB((kt + 1) & 1, (kt + 1) << 5);
    const char* Ab = (const char*)As[kt & 1];
    const char* Bb = (const char*)Bs[kt & 1];
    short8 af[4], bf[4];
#pragma unroll
    for (int m = 0; m < 4; ++m)
      af[m] = *(const short8*)(Ab + ((wr * 64 + m * 16 + (l & 15)) << 6) + ((l >> 4) << 4));
#pragma unroll
    for (int n = 0; n < 4; ++n)
      bf[n] = *(const short8*)(Bb + ((wc * 64 + n * 16 + (l & 15)) << 6) + ((l >> 4) << 4));
    __builtin_amdgcn_s_setprio(1);
#pragma unroll
    for (int m = 0; m < 4; ++m)
#pragma unroll
      for (int n = 0; n < 4; ++n)
        acc[m][n] = __builtin_amdgcn_mfma_f32_16x16x32_bf16(af[m], bf[n], acc[m][n], 0, 0, 0);
    __builtin_amdgcn_s_setprio(0);
  }

#pragma unroll
  for (int m = 0; m < 4; ++m) {
    int row0 = m0 + wr * 64 + m * 16 + ((l >> 4) << 2);
#pragma unroll
    for (int n = 0; n < 4; ++n) {
      int col = n0 + wc * 64 + n * 16 + (l & 15);
#pragma unroll
      for (int j = 0; j < 4; ++j)
        C[(size_t)(row0 + j) * ldc + col] = acc[m][n][j];
    }
  }
}

// ---------------------------------------------------------------------------
// post: normrope ([0,4096)) + V transpose-cast ([4096,4352)) in one launch.
// ---------------------------------------------------------------------------
__global__ __launch_bounds__(256) void post_kernel(const float* __restrict__ qkv,
                                                   u16* __restrict__ Qbf,
                                                   u16* __restrict__ Kbf,
                                                   u16* __restrict__ Vt) {
  __shared__ float tt[64][65];
  const int bid = blockIdx.x;
  if (bid < 4096) {
    const int t = bid;
    const int pos = t & 2047, b = t >> 11;
    const int wv = threadIdx.x >> 6, lane = threadIdx.x & 63;
    const int fi = lane & 31;
    const float invf = 1.0f / powf(10000.0f, (float)fi * (1.0f / 32.0f));
    float sn, cs; sincosf((float)pos * invf, &sn, &cs);
    const float* row = qkv + (size_t)t * 1536;
#pragma unroll
    for (int hh = 0; hh < 4; ++hh) {
      const int h = wv * 4 + hh;
      float val = row[h * 64 + lane];
      float ss = val * val;
#pragma unroll
      for (int off = 32; off; off >>= 1) ss += __shfl_xor(ss, off);
      val *= rsqrtf(ss * (1.f / 64.f) + 1e-5f);
      float partner = __shfl_xor(val, 32);
      float o = (lane < 32) ? (val * cs - partner * sn) : (val * cs + partner * sn);
      Qbf[((size_t)(b * 16 + h) * 2048 + pos) * 64 + lane] = f2bf(o * 0.0025f);
    }
    {
      float val = row[1024 + wv * 64 + lane];
      float ss = val * val;
#pragma unroll
      for (int off = 32; off; off >>= 1) ss += __shfl_xor(ss, off);
      val *= rsqrtf(ss * (1.f / 64.f) + 1e-5f);
      float partner = __shfl_xor(val, 32);
      float o = (lane < 32) ? (val * cs - partner * sn) : (val * cs + partner * sn);
      Kbf[((size_t)(b * 4 + wv) * 2048 + pos) * 64 + lane] = f2bf(o);
    }
    return;
  }
  const int t2 = bid - 4096;
  const int bkv = t2 >> 5;
  const int s0 = (t2 & 31) << 6;
  const int r = threadIdx.x >> 4, c4 = (threadIdx.x & 15) << 2;
#pragma unroll
  for (int i = 0; i < 4; ++i) {
    int row = r + (i << 4);
    const float* g = qkv + (size_t)(((bkv >> 2) * 2048 + s0 + row)) * 1536
                   + 1280 + ((bkv & 3) << 6) + c4;
    float4 v = *(const float4*)g;
    tt[row][c4] = v.x; tt[row][c4 + 1] = v.y; tt[row][c4 + 2] = v.z; tt[row][c4 + 3] = v.w;
  }
  __syncthreads();
#pragma unroll
  for (int i = 0; i < 4; ++i) {
    int d = r + (i << 4);
    uint2 u;
    u.x = pk2(tt[c4][d], tt[c4 + 1][d]);
    u.y = pk2(tt[c4 + 2][d], tt[c4 + 3][d]);
    *(uint2*)(Vt + (size_t)(bkv * 64 + d) * 2048 + s0 + c4) = u;
  }
}

// ---------------------------------------------------------------------------
// Flash attention.  Fixed-max softmax (scores hard-bounded: |50*tanh| < 8 ->
// p = exp(sc-8), no running max/rescale).  Softcap via odd polynomial:
// z = qk/400 in [-0.16,0.16], tanh(z) ~= z(1 - z^2/3 + 2z^4/15) -> 1 TRANS
// per score instead of 3.  Block = 128 thr (2 waves x 32 q-rows), QBLK=64,
// KVBLK=64 double-buffered, DIRECT global->LDS staging (short live ranges --
// r3's reg-staging spilled: WRITE_SIZE 8MB->80MB).  Blocks >= 1024: wo tcast.
// ---------------------------------------------------------------------------
__device__ __forceinline__ short8 rdfrag(const uint4* lds, int row, int cb) {
  int byte = ((row << 7) + cb) ^ ((row & 7) << 4);
  return *(const short8*)((const char*)lds + byte);
}

__global__ __launch_bounds__(128, 2) void attn_kernel(const u16* __restrict__ Qbf,
                                                      const u16* __restrict__ Kbf,
                                                      const u16* __restrict__ Vt,
                                                      u16* __restrict__ ybf,
                                                      const float* __restrict__ wo,
                                                      u16* __restrict__ woT) {
  __shared__ uint4 KV[4][512];         // K0 V0 K1 V1, 64x64 bf16, XOR-swizzled
  const int tid = threadIdx.x;

  if (blockIdx.x >= 1024) {            // ---- wo transpose-cast tail blocks ----
    float* tt = (float*)KV;            // 32x33 f32 tile
    const int t = blockIdx.x - 1024;
    const int n0 = (t & 31) << 5, k0 = (t >> 5) << 5;
    const int x = tid & 31, y = tid >> 5;          // y: 0..3
#pragma unroll
    for (int i = 0; i < 8; ++i) {
      int r = y + (i << 2);
      tt[r * 33 + x] = wo[(size_t)(k0 + r) * 1024 + n0 + x];
    }
    __syncthreads();
#pragma unroll
    for (int i = 0; i < 8; ++i) {
      int r = y + (i << 2);
      woT[(size_t)(n0 + r) * 1024 + k0 + x] = f2bf(tt[x * 33 + r]);
    }
    return;
  }

  const int bh = blockIdx.x & 31;
  const int qt = 31 - (blockIdx.x >> 5);   // heavy q-tiles dispatch first
  const int q0 = qt << 6;
  const int w = tid >> 6, l = tid & 63;
  const int ql = l & 31, myh = l >> 5;
  const int b = bh >> 4, h = bh & 15, hkv = h >> 2;
  const int qg = q0 + (w << 5) + ql;

  const u16* Kg = Kbf + (((size_t)(b * 4 + hkv)) << 11) * 64;
  const u16* Vg = Vt + (((size_t)(b * 4 + hkv)) << 6) * 2048;

  short8 bq[4];
  {
    const u16* Qg = Qbf + ((size_t)((b * 16 + h) * 2048 + qg)) * 64 + myh * 8;
    bq[0] = *(const short8*)(Qg);
    bq[1] = *(const short8*)(Qg + 16);
    bq[2] = *(const short8*)(Qg + 32);
    bq[3] = *(const short8*)(Qg + 48);
  }

  f32x16 o0, o1;
#pragma unroll
  for (int i = 0; i < 16; ++i) { o0[i] = 0.f; o1[i] = 0.f; }
  float l_run = 0.f;

  const int KT = qt + 1;

  // direct global->LDS stage (load + immediate swizzled write; no long-lived regs)
  auto stage = [&](int buf, int kt) {
    const u16* gk = Kg + ((size_t)(kt << 6)) * 64;
    const u16* gv = Vg + (kt << 6);
#pragma unroll
    for (int i = 0; i < 4; ++i) {
      int c = tid + (i << 7);            // 0..511 16B chunks
      int row = c >> 3, off = c & 7;
      uint4 kk4 = *(const uint4*)(gk + row * 64 + (off << 3));
      uint4 vv4 = *(const uint4*)(gv + (size_t)row * 2048 + (off << 3));
      int byte = ((row << 7) + (off << 4)) ^ ((row & 7) << 4);
      *(uint4*)((char*)KV[buf << 1] + byte) = kk4;
      *(uint4*)((char*)KV[(buf << 1) + 1] + byte) = vv4;
    }
  };

  stage(0, 0);

  const float PC2 = -0.33333333f;        // -1/3
  const float PC4 = 0.13333333f;         //  2/15
  const float SC1 = 72.13475204444817f;  // 50*log2(e)
  const float SC0 = -11.541560327111708f;// -8*log2(e)

#pragma unroll 1
  for (int kt = 0; kt < KT; ++kt) {
    const int k0 = kt << 6;
    const int buf = kt & 1;
    __syncthreads();                     // stage(kt) visible; prior tile done
    if (kt + 1 < KT) stage(buf ^ 1, kt + 1);
    const bool full = (k0 + 63 <= q0 + (w << 5));
    const uint4* Kl = KV[buf << 1];
    const uint4* Vl = KV[(buf << 1) + 1];

    f32x16 s0, s1;                       // scores^T: col = q(l&31), row = k
#pragma unroll
    for (int i = 0; i < 16; ++i) { s0[i] = 0.f; s1[i] = 0.f; }
    __builtin_amdgcn_s_setprio(1);
#pragma unroll
    for (int c = 0; c < 4; ++c) {
      short8 ak = rdfrag(Kl, ql, (c << 5) + (myh << 4));
      s0 = __builtin_amdgcn_mfma_f32_32x32x16_bf16(ak, bq[c], s0, 0, 0, 0);
    }
#pragma unroll
    for (int c = 0; c < 4; ++c) {
      short8 ak = rdfrag(Kl, 32 + ql, (c << 5) + (myh << 4));
      s1 = __builtin_amdgcn_mfma_f32_32x32x16_bf16(ak, bq[c], s1, 0, 0, 0);
    }
    __builtin_amdgcn_s_setprio(0);

    // p = exp2(SC1 * z*poly(z^2) + SC0),  z = qk/400 (folded into Q)
    float lsum = 0.f;
    if (full) {
#pragma unroll
      for (int i = 0; i < 16; ++i) {
        float z = s0[i];
        float t2 = z * z;
        float pw = fmaf(t2, fmaf(t2, PC4, PC2), 1.0f);
        float p = exp2fast(fmaf(z * pw, SC1, SC0));
        s0[i] = p; lsum += p;
      }
#pragma unroll
      for (int i = 0; i < 16; ++i) {
        float z = s1[i];
        float t2 = z * z;
        float pw = fmaf(t2, fmaf(t2, PC4, PC2), 1.0f);
        float p = exp2fast(fmaf(z * pw, SC1, SC0));
        s1[i] = p; lsum += p;
      }
    } else {
#pragma unroll
      for (int i = 0; i < 16; ++i) {
        int kk = k0 + (i & 3) + ((i >> 2) << 3) + (myh << 2);
        float z = s0[i];
        float t2 = z * z;
        float pw = fmaf(t2, fmaf(t2, PC4, PC2), 1.0f);
        float p = exp2fast(fmaf(z * pw, SC1, SC0));
        p = (kk <= qg) ? p : 0.f;
        s0[i] = p; lsum += p;
      }
#pragma unroll
      for (int i = 0; i < 16; ++i) {
        int kk = k0 + 32 + (i & 3) + ((i >> 2) << 3) + (myh << 2);
        float z = s1[i];
        float t2 = z * z;
        float pw = fmaf(t2, fmaf(t2, PC4, PC2), 1.0f);
        float p = exp2fast(fmaf(z * pw, SC1, SC0));
        p = (kk <= qg) ? p : 0.f;
        s1[i] = p; lsum += p;
      }
    }
    l_run += lsum;

    // P -> bf16 B-frags: pa[c][j] = P[q = l&31][k = c*16 + myh*8 + j]
    short8 pa[4];
#pragma unroll
    for (int c = 0; c < 4; ++c) {
      const f32x16& P = (c < 2) ? s0 : s1;
      const int rb = (c & 1) << 3;
      u32 A = cvtpk(P[rb + 0], P[rb + 1]);
      u32 Cw = cvtpk(P[rb + 2], P[rb + 3]);
      u32 B = cvtpk(P[rb + 4], P[rb + 5]);
      u32 D = cvtpk(P[rb + 6], P[rb + 7]);
      plswap(A, B); plswap(Cw, D);
      union { u32 u[4]; short8 s; } pw_;
      pw_.u[0] = A; pw_.u[1] = Cw; pw_.u[2] = B; pw_.u[3] = D;
      pa[c] = pw_.s;
    }

    // O^T += V^T * P^T
    __builtin_amdgcn_s_setprio(1);
#pragma unroll
    for (int c = 0; c < 4; ++c) {
      short8 av = rdfrag(Vl, ql, (c << 5) + (myh << 4));
      o0 = __builtin_amdgcn_mfma_f32_32x32x16_bf16(av, pa[c], o0, 0, 0, 0);
    }
#pragma unroll
    for (int c = 0; c < 4; ++c) {
      short8 av = rdfrag(Vl, 32 + ql, (c << 5) + (myh << 4));
      o1 = __builtin_amdgcn_mfma_f32_32x32x16_bf16(av, pa[c], o1, 0, 0, 0);
    }
    __builtin_amdgcn_s_setprio(0);
  }

  float lr = l_run + __shfl_xor(l_run, 32);
  float rl = rcpfast(lr);
  u16* yr = ybf + ((size_t)(b * 2048 + qg)) * 1024 + h * 64;
#pragma unroll
  for (int i = 0; i < 16; i += 2) {
    int dof = (i & 3) + ((i >> 2) << 3) + (myh << 2);
    *(u32*)(yr + dof) = cvtpk(o0[i] * rl, o0[i + 1] * rl);
    *(u32*)(yr + 32 + dof) = cvtpk(o1[i] * rl, o1[i + 1] * rl);
  }
}

// ---------------------------------------------------------------------------
extern "C" void kernel_launch(void* const* d_in, const int* in_sizes, int n_in,
                              void* d_out, int out_size, void* d_ws, size_t ws_size,
                              hipStream_t stream) {
  (void)in_sizes; (void)n_in; (void)out_size; (void)ws_size;
  const float* x  = (const float*)d_in[0];
  const float* wq = (const float*)d_in[1];
  const float* wk = (const float*)d_in[2];
  const float* wv = (const float*)d_in[3];
  const float* wo = (const float*)d_in[4];
  float* out = (float*)d_out;

  char* ws = (char*)d_ws;
  float* qkv = (float*)ws;               // [0, 24M) f32, dead after post
  u16* ybf = (u16*)ws;                   // [0, 8M)  alias (attn output)
  u16* woT = (u16*)(ws + (8u << 20));    // [8, 10M) alias (written in attn launch)
  u16* wT  = (u16*)(ws + (24u << 20));   // [24, 27M)
  u16* Qbf = (u16*)(ws + (27u << 20));   // [27, 35M)
  u16* Kbf = (u16*)(ws + (35u << 20));   // [35, 37M)
  u16* Vt  = (u16*)(ws + (37u << 20));   // [37, 39M)

  prep_kernel<<<dim3(1536), 256, 0, stream>>>(wq, wk, wv, wT);
  gemm_kernel<true><<<dim3(12, 32), 256, 0, stream>>>(x, wT, qkv, 1024, 1536);
  post_kernel<<<dim3(4352), 256, 0, stream>>>(qkv, Qbf, Kbf, Vt);
  attn_kernel<<<dim3(2048), 128, 0, stream>>>(Qbf, Kbf, Vt, ybf, wo, woT);
  gemm_kernel<false><<<dim3(8, 32), 256, 0, stream>>>(ybf, woT, out, 1024, 1024);
}

// Round 5
// 106.052 us; speedup vs baseline: 1.7358x; 1.2859x over previous
//
#include <hip/hip_runtime.h>
#include <hip/hip_bf16.h>
#include <math.h>

#define D_MODEL 1024
#define N_HEADS 16
#define N_KV 4
#define HEAD_DIM 64
#define SEQ 2048
#define BATCH 2
#define M_TOK (BATCH * SEQ)

typedef unsigned int u32;
typedef unsigned short u16;
typedef __attribute__((ext_vector_type(8))) short short8;
typedef __attribute__((ext_vector_type(4))) float f32x4;
typedef __attribute__((ext_vector_type(16))) float f32x16;

#define AS1 __attribute__((address_space(1)))
#define AS3 __attribute__((address_space(3)))

__device__ __forceinline__ u16 f2bf(float f) {
  union { __hip_bfloat16 h; u16 u; } c; c.h = __float2bfloat16(f); return c.u;
}
__device__ __forceinline__ u32 cvtpk(float lo, float hi) {
  u32 r; asm("v_cvt_pk_bf16_f32 %0, %1, %2" : "=v"(r) : "v"(lo), "v"(hi)); return r;
}
__device__ __forceinline__ void plswap(u32& a, u32& b) {
  asm volatile("v_permlane32_swap_b32 %0, %1" : "+v"(a), "+v"(b));
}
__device__ __forceinline__ float exp2fast(float x) { return __builtin_amdgcn_exp2f(x); }
__device__ __forceinline__ float rcpfast(float x) { return __builtin_amdgcn_rcpf(x); }

// ---------------------------------------------------------------------------
// prep: x cast to bf16 ([0,512)) + wq/wk/wv transpose-cast ([512,2048)) +
// wo transpose-cast ([2048,3072)).  wT[n][k] = bf16(w[k][n]), stride 1024.
// ---------------------------------------------------------------------------
__global__ __launch_bounds__(256) void prep_kernel(const float* __restrict__ x,
                                                   const float* __restrict__ wq,
                                                   const float* __restrict__ wk,
                                                   const float* __restrict__ wv,
                                                   const float* __restrict__ wo,
                                                   u16* __restrict__ xb,
                                                   u16* __restrict__ wT,
                                                   u16* __restrict__ woT) {
  int bx = blockIdx.x;
  if (bx < 512) {                       // ---- x -> bf16, 8192 elems/block ----
    const size_t base = (size_t)bx * 8192;
#pragma unroll
    for (int j = 0; j < 4; ++j) {
      size_t e = base + j * 2048 + threadIdx.x * 8;
      float4 f0 = *(const float4*)(x + e);
      float4 f1 = *(const float4*)(x + e + 4);
      uint4 u;
      u.x = cvtpk(f0.x, f0.y); u.y = cvtpk(f0.z, f0.w);
      u.z = cvtpk(f1.x, f1.y); u.w = cvtpk(f1.z, f1.w);
      *(uint4*)(xb + e) = u;
    }
    return;
  }
  bx -= 512;
  __shared__ float t[32][33];
  const float* src; u16* dst; int N, ntm, nts;
  if (bx < 1024)      { src = wq; dst = wT;                 N = 1024; ntm = 31; nts = 5; }
  else if (bx < 1280) { bx -= 1024; src = wk; dst = wT + (1024 << 10); N = 256; ntm = 7; nts = 3; }
  else if (bx < 1536) { bx -= 1280; src = wv; dst = wT + (1280 << 10); N = 256; ntm = 7; nts = 3; }
  else                { bx -= 1536; src = wo; dst = woT;    N = 1024; ntm = 31; nts = 5; }
  const int n0 = (bx & ntm) << 5, k0 = (bx >> nts) << 5;
  const int xx = threadIdx.x & 31, y = threadIdx.x >> 5;
#pragma unroll
  for (int i = 0; i < 4; ++i) {
    int r = y + (i << 3);
    t[r][xx] = src[(size_t)(k0 + r) * N + n0 + xx];
  }
  __syncthreads();
#pragma unroll
  for (int i = 0; i < 4; ++i) {
    int r = y + (i << 3);
    dst[(size_t)(n0 + r) * 1024 + k0 + xx] = f2bf(t[xx][r]);
  }
}

// ---------------------------------------------------------------------------
// QKV GEMM with fused RMSNorm+RoPE+layout epilogue.
// C[4096][1536] = xb @ wT^T; 128x128 tile, BK=32, 256 thr, double-buffered,
// XCD-swizzled (4 m-tiles x 12 n-tiles per XCD -> A panel + B L2-resident).
// Each wave's 64x64 quadrant = one head x 64 tokens: norm = 16-lane shfl
// reduce; RoPE pairs (d,d+32) = frags (n,n+2) register-local.  Outputs
// written bf16 via swizzled LDS (staging buffers reused) for coalescing.
//   nb<8: Qbf[b][h][s][64] (x 1/(8*CAP));  nb 8,9: Kbf[b][kvh][s][64];
//   nb 10,11: Vt[b][kvh][d][s] (transposed in LDS).
// ---------------------------------------------------------------------------
__global__ __launch_bounds__(256, 2) void qkvgemm_kernel(const u16* __restrict__ xb,
                                                         const u16* __restrict__ wT,
                                                         u16* __restrict__ Qbf,
                                                         u16* __restrict__ Kbf,
                                                         u16* __restrict__ Vt) {
  __shared__ uint4 SM[4][512];          // A0 A1 B0 B1, 8KB each
  const int tid = threadIdx.x;
  const int w = tid >> 6, l = tid & 63;
  const int wr = w >> 1, wc = w & 1;
  int wg = ((int)blockIdx.x & 7) * 48 + ((int)blockIdx.x >> 3);
  const int mt = wg / 12, nb = wg - mt * 12;
  const int m0 = mt << 7;

  f32x4 acc[4][4];
#pragma unroll
  for (int m = 0; m < 4; ++m)
#pragma unroll
    for (int n = 0; n < 4; ++n)
#pragma unroll
      for (int j = 0; j < 4; ++j) acc[m][n][j] = 0.f;

  auto stage = [&](int buf, int k0) {
    const u16* Ab = xb + (size_t)m0 * 1024 + k0;
#pragma unroll
    for (int r = 0; r < 2; ++r) {
      int i = (w << 1) + r;
      int row = (i << 4) + (l >> 2);
      const u16* g = Ab + (size_t)row * 1024 + ((l & 3) << 3);
      __builtin_amdgcn_global_load_lds((const AS1 void*)g,
          (AS3 void*)((char*)SM + (buf << 13) + (i << 10)), 16, 0, 0);
    }
    const u16* Bb = wT + (size_t)(nb << 7) * 1024 + k0;
#pragma unroll
    for (int r = 0; r < 2; ++r) {
      int i = (w << 1) + r;
      int row = (i << 4) + (l >> 2);
      const u16* g = Bb + (size_t)row * 1024 + ((l & 3) << 3);
      __builtin_amdgcn_global_load_lds((const AS1 void*)g,
          (AS3 void*)((char*)SM + ((2 + buf) << 13) + (i << 10)), 16, 0, 0);
    }
  };

  stage(0, 0);
#pragma unroll 1
  for (int kt = 0; kt < 32; ++kt) {
    __syncthreads();
    if (kt + 1 < 32) stage((kt + 1) & 1, (kt + 1) << 5);
    const char* Ab = (const char*)SM + ((kt & 1) << 13);
    const char* Bb = (const char*)SM + ((2 + (kt & 1)) << 13);
    short8 af[4], bf[4];
#pragma unroll
    for (int m = 0; m < 4; ++m)
      af[m] = *(const short8*)(Ab + ((wr * 64 + m * 16 + (l & 15)) << 6) + ((l >> 4) << 4));
#pragma unroll
    for (int n = 0; n < 4; ++n)
      bf[n] = *(const short8*)(Bb + ((wc * 64 + n * 16 + (l & 15)) << 6) + ((l >> 4) << 4));
#pragma unroll
    for (int m = 0; m < 4; ++m)
#pragma unroll
      for (int n = 0; n < 4; ++n)
        acc[m][n] = __builtin_amdgcn_mfma_f32_16x16x32_bf16(af[m], bf[n], acc[m][n], 0, 0, 0);
  }

  __syncthreads();                      // all MFMA LDS reads done; SM reusable
  const int b = m0 >> 11;
  const int pos0 = (m0 & 2047) + wr * 64;
  const int lg = l >> 4, lc = l & 15;
  u16* lds = (u16*)((char*)SM + (w << 13));   // wave-private 8KB scratch

  if (nb < 10) {
    // row RMSNorm: ssq over 4 n-frags x 16 lanes sharing the row
    float rs[4][4];
#pragma unroll
    for (int m = 0; m < 4; ++m)
#pragma unroll
      for (int j = 0; j < 4; ++j) {
        float ssq = 0.f;
#pragma unroll
        for (int n = 0; n < 4; ++n) ssq = fmaf(acc[m][n][j], acc[m][n][j], ssq);
        ssq += __shfl_xor(ssq, 1); ssq += __shfl_xor(ssq, 2);
        ssq += __shfl_xor(ssq, 4); ssq += __shfl_xor(ssq, 8);
        rs[m][j] = rsqrtf(ssq * (1.f / 64.f) + 1e-5f);
      }
    const float osc = (nb < 8) ? 0.0025f : 1.0f;   // 1/(8*CAP) folded into Q
    const float invf0 = powf(10000.0f, (float)lc * (-1.f / 32.f));
    const float invf1 = powf(10000.0f, (float)(lc + 16) * (-1.f / 32.f));
#pragma unroll
    for (int m = 0; m < 4; ++m) {
#pragma unroll
      for (int j = 0; j < 4; ++j) {
        const int row = m * 16 + lg * 4 + j;
        const float pos = (float)(pos0 + row);
        float s0, c0, s1, c1;
        sincosf(pos * invf0, &s0, &c0);
        sincosf(pos * invf1, &s1, &c1);
        const float r_ = rs[m][j];
        float x0 = acc[m][0][j] * r_, x1 = acc[m][1][j] * r_;
        float x2 = acc[m][2][j] * r_, x3 = acc[m][3][j] * r_;
        u16 o0 = f2bf((x0 * c0 - x2 * s0) * osc);
        u16 o1 = f2bf((x1 * c1 - x3 * s1) * osc);
        u16 o2 = f2bf((x2 * c0 + x0 * s0) * osc);
        u16 o3 = f2bf((x3 * c1 + x1 * s1) * osc);
        const int rb = row << 6, xr = (row & 7) << 3;
        lds[rb + (lc ^ xr)] = o0;
        lds[rb + ((16 + lc) ^ xr)] = o1;
        lds[rb + ((32 + lc) ^ xr)] = o2;
        lds[rb + ((48 + lc) ^ xr)] = o3;
      }
    }
  } else {
    // V: store transposed [d][tok] (4 consecutive tokens packed per uint2)
#pragma unroll
    for (int m = 0; m < 4; ++m)
#pragma unroll
      for (int n = 0; n < 4; ++n) {
        const int d = n * 16 + lc;
        const int tok = m * 16 + lg * 4;
        uint2 u;
        u.x = cvtpk(acc[m][n][0], acc[m][n][1]);
        u.y = cvtpk(acc[m][n][2], acc[m][n][3]);
        *(uint2*)(lds + (d << 6) + (tok ^ ((d & 7) << 3))) = u;
      }
  }
  __syncthreads();

  u16* gp; int rstride;
  if (nb < 8)       { gp = Qbf + ((size_t)((b * 16 + nb * 2 + wc) * 2048 + pos0) << 6); rstride = 64; }
  else if (nb < 10) { gp = Kbf + ((size_t)((b * 4 + (nb - 8) * 2 + wc) * 2048 + pos0) << 6); rstride = 64; }
  else              { gp = Vt + (((size_t)((b * 4 + (nb - 10) * 2 + wc) * 64)) << 11) + pos0; rstride = 2048; }
#pragma unroll
  for (int ic = 0; ic < 8; ++ic) {
    const int c = (ic << 6) + l;
    const int row = c >> 3, col8 = (c & 7) << 3;
    uint4 v = *(const uint4*)(lds + (row << 6) + (col8 ^ ((row & 7) << 3)));
    *(uint4*)(gp + (size_t)row * rstride + col8) = v;
  }
}

// ---------------------------------------------------------------------------
// Output projection: out[4096][1024] f32 = ybf @ woT^T.  Same GEMM core,
// XCD-swizzled (4 m-tiles x 8 n-tiles per XCD).
// ---------------------------------------------------------------------------
__global__ __launch_bounds__(256, 2) void gemm_kernel(const u16* __restrict__ A,
                                                      const u16* __restrict__ BT,
                                                      float* __restrict__ C) {
  __shared__ uint4 SM[4][512];
  const int tid = threadIdx.x;
  const int w = tid >> 6, l = tid & 63;
  const int wr = w >> 1, wc = w & 1;
  int wg = ((int)blockIdx.x & 7) * 32 + ((int)blockIdx.x >> 3);
  const int m0 = (wg >> 3) << 7, n0 = (wg & 7) << 7;

  f32x4 acc[4][4];
#pragma unroll
  for (int m = 0; m < 4; ++m)
#pragma unroll
    for (int n = 0; n < 4; ++n)
#pragma unroll
      for (int j = 0; j < 4; ++j) acc[m][n][j] = 0.f;

  auto stage = [&](int buf, int k0) {
    const u16* Ab = A + (size_t)m0 * 1024 + k0;
#pragma unroll
    for (int r = 0; r < 2; ++r) {
      int i = (w << 1) + r;
      int row = (i << 4) + (l >> 2);
      const u16* g = Ab + (size_t)row * 1024 + ((l & 3) << 3);
      __builtin_amdgcn_global_load_lds((const AS1 void*)g,
          (AS3 void*)((char*)SM + (buf << 13) + (i << 10)), 16, 0, 0);
    }
    const u16* Bb = BT + (size_t)n0 * 1024 + k0;
#pragma unroll
    for (int r = 0; r < 2; ++r) {
      int i = (w << 1) + r;
      int row = (i << 4) + (l >> 2);
      const u16* g = Bb + (size_t)row * 1024 + ((l & 3) << 3);
      __builtin_amdgcn_global_load_lds((const AS1 void*)g,
          (AS3 void*)((char*)SM + ((2 + buf) << 13) + (i << 10)), 16, 0, 0);
    }
  };

  stage(0, 0);
#pragma unroll 1
  for (int kt = 0; kt < 32; ++kt) {
    __syncthreads();
    if (kt + 1 < 32) stage((kt + 1) & 1, (kt + 1) << 5);
    const char* Ab = (const char*)SM + ((kt & 1) << 13);
    const char* Bb = (const char*)SM + ((2 + (kt & 1)) << 13);
    short8 af[4], bf[4];
#pragma unroll
    for (int m = 0; m < 4; ++m)
      af[m] = *(const short8*)(Ab + ((wr * 64 + m * 16 + (l & 15)) << 6) + ((l >> 4) << 4));
#pragma unroll
    for (int n = 0; n < 4; ++n)
      bf[n] = *(const short8*)(Bb + ((wc * 64 + n * 16 + (l & 15)) << 6) + ((l >> 4) << 4));
#pragma unroll
    for (int m = 0; m < 4; ++m)
#pragma unroll
      for (int n = 0; n < 4; ++n)
        acc[m][n] = __builtin_amdgcn_mfma_f32_16x16x32_bf16(af[m], bf[n], acc[m][n], 0, 0, 0);
  }

#pragma unroll
  for (int m = 0; m < 4; ++m) {
    int row0 = m0 + wr * 64 + m * 16 + ((l >> 4) << 2);
#pragma unroll
    for (int n = 0; n < 4; ++n) {
      int col = n0 + wc * 64 + n * 16 + (l & 15);
#pragma unroll
      for (int j = 0; j < 4; ++j)
        C[(size_t)(row0 + j) * 1024 + col] = acc[m][n][j];
    }
  }
}

// ---------------------------------------------------------------------------
// Flash attention (unchanged from r4 core): fixed-max softmax (|50*tanh|<8 ->
// p=exp(sc-8)), poly-tanh softcap (1 TRANS/score), 128 thr (2 waves x 32
// q-rows), QBLK=64, KVBLK=64 double-buffered direct global->LDS staging.
// ---------------------------------------------------------------------------
__device__ __forceinline__ short8 rdfrag(const uint4* lds, int row, int cb) {
  int byte = ((row << 7) + cb) ^ ((row & 7) << 4);
  return *(const short8*)((const char*)lds + byte);
}

__global__ __launch_bounds__(128, 2) void attn_kernel(const u16* __restrict__ Qbf,
                                                      const u16* __restrict__ Kbf,
                                                      const u16* __restrict__ Vt,
                                                      u16* __restrict__ ybf) {
  __shared__ uint4 KV[4][512];         // K0 V0 K1 V1, 64x64 bf16, XOR-swizzled
  const int tid = threadIdx.x;
  const int bh = blockIdx.x & 31;
  const int qt = 31 - (blockIdx.x >> 5);   // heavy q-tiles dispatch first
  const int q0 = qt << 6;
  const int w = tid >> 6, l = tid & 63;
  const int ql = l & 31, myh = l >> 5;
  const int b = bh >> 4, h = bh & 15, hkv = h >> 2;
  const int qg = q0 + (w << 5) + ql;

  const u16* Kg = Kbf + (((size_t)(b * 4 + hkv)) << 11) * 64;
  const u16* Vg = Vt + (((size_t)(b * 4 + hkv)) << 6) * 2048;

  short8 bq[4];
  {
    const u16* Qg = Qbf + ((size_t)((b * 16 + h) * 2048 + qg)) * 64 + myh * 8;
    bq[0] = *(const short8*)(Qg);
    bq[1] = *(const short8*)(Qg + 16);
    bq[2] = *(const short8*)(Qg + 32);
    bq[3] = *(const short8*)(Qg + 48);
  }

  f32x16 o0, o1;
#pragma unroll
  for (int i = 0; i < 16; ++i) { o0[i] = 0.f; o1[i] = 0.f; }
  float l_run = 0.f;

  const int KT = qt + 1;

  auto stage = [&](int buf, int kt) {
    const u16* gk = Kg + ((size_t)(kt << 6)) * 64;
    const u16* gv = Vg + (kt << 6);
#pragma unroll
    for (int i = 0; i < 4; ++i) {
      int c = tid + (i << 7);
      int row = c >> 3, off = c & 7;
      uint4 kk4 = *(const uint4*)(gk + row * 64 + (off << 3));
      uint4 vv4 = *(const uint4*)(gv + (size_t)row * 2048 + (off << 3));
      int byte = ((row << 7) + (off << 4)) ^ ((row & 7) << 4);
      *(uint4*)((char*)KV[buf << 1] + byte) = kk4;
      *(uint4*)((char*)KV[(buf << 1) + 1] + byte) = vv4;
    }
  };

  stage(0, 0);

  const float PC2 = -0.33333333f;        // -1/3
  const float PC4 = 0.13333333f;         //  2/15
  const float SC1 = 72.13475204444817f;  // 50*log2(e)
  const float SC0 = -11.541560327111708f;// -8*log2(e)

#pragma unroll 1
  for (int kt = 0; kt < KT; ++kt) {
    const int k0 = kt << 6;
    const int buf = kt & 1;
    __syncthreads();
    if (kt + 1 < KT) stage(buf ^ 1, kt + 1);
    const bool full = (k0 + 63 <= q0 + (w << 5));
    const uint4* Kl = KV[buf << 1];
    const uint4* Vl = KV[(buf << 1) + 1];

    f32x16 s0, s1;                       // scores^T: col = q(l&31), row = k
#pragma unroll
    for (int i = 0; i < 16; ++i) { s0[i] = 0.f; s1[i] = 0.f; }
    __builtin_amdgcn_s_setprio(1);
#pragma unroll
    for (int c = 0; c < 4; ++c) {
      short8 ak = rdfrag(Kl, ql, (c << 5) + (myh << 4));
      s0 = __builtin_amdgcn_mfma_f32_32x32x16_bf16(ak, bq[c], s0, 0, 0, 0);
    }
#pragma unroll
    for (int c = 0; c < 4; ++c) {
      short8 ak = rdfrag(Kl, 32 + ql, (c << 5) + (myh << 4));
      s1 = __builtin_amdgcn_mfma_f32_32x32x16_bf16(ak, bq[c], s1, 0, 0, 0);
    }
    __builtin_amdgcn_s_setprio(0);

    float lsum = 0.f;
    if (full) {
#pragma unroll
      for (int i = 0; i < 16; ++i) {
        float z = s0[i];
        float t2 = z * z;
        float pw = fmaf(t2, fmaf(t2, PC4, PC2), 1.0f);
        float p = exp2fast(fmaf(z * pw, SC1, SC0));
        s0[i] = p; lsum += p;
      }
#pragma unroll
      for (int i = 0; i < 16; ++i) {
        float z = s1[i];
        float t2 = z * z;
        float pw = fmaf(t2, fmaf(t2, PC4, PC2), 1.0f);
        float p = exp2fast(fmaf(z * pw, SC1, SC0));
        s1[i] = p; lsum += p;
      }
    } else {
#pragma unroll
      for (int i = 0; i < 16; ++i) {
        int kk = k0 + (i & 3) + ((i >> 2) << 3) + (myh << 2);
        float z = s0[i];
        float t2 = z * z;
        float pw = fmaf(t2, fmaf(t2, PC4, PC2), 1.0f);
        float p = exp2fast(fmaf(z * pw, SC1, SC0));
        p = (kk <= qg) ? p : 0.f;
        s0[i] = p; lsum += p;
      }
#pragma unroll
      for (int i = 0; i < 16; ++i) {
        int kk = k0 + 32 + (i & 3) + ((i >> 2) << 3) + (myh << 2);
        float z = s1[i];
        float t2 = z * z;
        float pw = fmaf(t2, fmaf(t2, PC4, PC2), 1.0f);
        float p = exp2fast(fmaf(z * pw, SC1, SC0));
        p = (kk <= qg) ? p : 0.f;
        s1[i] = p; lsum += p;
      }
    }
    l_run += lsum;

    short8 pa[4];
#pragma unroll
    for (int c = 0; c < 4; ++c) {
      const f32x16& P = (c < 2) ? s0 : s1;
      const int rb = (c & 1) << 3;
      u32 A = cvtpk(P[rb + 0], P[rb + 1]);
      u32 Cw = cvtpk(P[rb + 2], P[rb + 3]);
      u32 B = cvtpk(P[rb + 4], P[rb + 5]);
      u32 D = cvtpk(P[rb + 6], P[rb + 7]);
      plswap(A, B); plswap(Cw, D);
      union { u32 u[4]; short8 s; } pw_;
      pw_.u[0] = A; pw_.u[1] = Cw; pw_.u[2] = B; pw_.u[3] = D;
      pa[c] = pw_.s;
    }

    __builtin_amdgcn_s_setprio(1);
#pragma unroll
    for (int c = 0; c < 4; ++c) {
      short8 av = rdfrag(Vl, ql, (c << 5) + (myh << 4));
      o0 = __builtin_amdgcn_mfma_f32_32x32x16_bf16(av, pa[c], o0, 0, 0, 0);
    }
#pragma unroll
    for (int c = 0; c < 4; ++c) {
      short8 av = rdfrag(Vl, 32 + ql, (c << 5) + (myh << 4));
      o1 = __builtin_amdgcn_mfma_f32_32x32x16_bf16(av, pa[c], o1, 0, 0, 0);
    }
    __builtin_amdgcn_s_setprio(0);
  }

  float lr = l_run + __shfl_xor(l_run, 32);
  float rl = rcpfast(lr);
  u16* yr = ybf + ((size_t)(b * 2048 + qg)) * 1024 + h * 64;
#pragma unroll
  for (int i = 0; i < 16; i += 2) {
    int dof = (i & 3) + ((i >> 2) << 3) + (myh << 2);
    *(u32*)(yr + dof) = cvtpk(o0[i] * rl, o0[i + 1] * rl);
    *(u32*)(yr + 32 + dof) = cvtpk(o1[i] * rl, o1[i + 1] * rl);
  }
}

// ---------------------------------------------------------------------------
extern "C" void kernel_launch(void* const* d_in, const int* in_sizes, int n_in,
                              void* d_out, int out_size, void* d_ws, size_t ws_size,
                              hipStream_t stream) {
  (void)in_sizes; (void)n_in; (void)out_size; (void)ws_size;
  const float* x  = (const float*)d_in[0];
  const float* wq = (const float*)d_in[1];
  const float* wk = (const float*)d_in[2];
  const float* wv = (const float*)d_in[3];
  const float* wo = (const float*)d_in[4];
  float* out = (float*)d_out;

  char* ws = (char*)d_ws;                // 33 MiB total, no aliasing
  u16* xb  = (u16*)ws;                   // [0, 8M)
  u16* ybf = (u16*)(ws + (8u << 20));    // [8, 16M)
  u16* woT = (u16*)(ws + (16u << 20));   // [16, 18M)
  u16* wT  = (u16*)(ws + (18u << 20));   // [18, 21M)
  u16* Qbf = (u16*)(ws + (21u << 20));   // [21, 29M)
  u16* Kbf = (u16*)(ws + (29u << 20));   // [29, 31M)
  u16* Vt  = (u16*)(ws + (31u << 20));   // [31, 33M)

  prep_kernel<<<dim3(3072), 256, 0, stream>>>(x, wq, wk, wv, wo, xb, wT, woT);
  qkvgemm_kernel<<<dim3(384), 256, 0, stream>>>(xb, wT, Qbf, Kbf, Vt);
  attn_kernel<<<dim3(1024), 128, 0, stream>>>(Qbf, Kbf, Vt, ybf);
  gemm_kernel<<<dim3(256), 256, 0, stream>>>(ybf, woT, out);
}

// Round 6
// 105.915 us; speedup vs baseline: 1.7381x; 1.0013x over previous
//
#include <hip/hip_runtime.h>
#include <hip/hip_bf16.h>
#include <math.h>

#define D_MODEL 1024
#define N_HEADS 16
#define N_KV 4
#define HEAD_DIM 64
#define SEQ 2048
#define BATCH 2
#define M_TOK (BATCH * SEQ)

typedef unsigned int u32;
typedef unsigned short u16;
typedef __attribute__((ext_vector_type(8))) short short8;
typedef __attribute__((ext_vector_type(4))) float f32x4;
typedef __attribute__((ext_vector_type(16))) float f32x16;
typedef __attribute__((ext_vector_type(2))) float f32x2;

#define AS1 __attribute__((address_space(1)))
#define AS3 __attribute__((address_space(3)))

__device__ __forceinline__ u16 f2bf(float f) {
  union { __hip_bfloat16 h; u16 u; } c; c.h = __float2bfloat16(f); return c.u;
}
__device__ __forceinline__ u32 cvtpk(float lo, float hi) {
  u32 r; asm("v_cvt_pk_bf16_f32 %0, %1, %2" : "=v"(r) : "v"(lo), "v"(hi)); return r;
}
__device__ __forceinline__ void plswap(u32& a, u32& b) {
  asm volatile("v_permlane32_swap_b32 %0, %1" : "+v"(a), "+v"(b));
}
__device__ __forceinline__ float exp2fast(float x) { return __builtin_amdgcn_exp2f(x); }
__device__ __forceinline__ float rcpfast(float x) { return __builtin_amdgcn_rcpf(x); }
__device__ __forceinline__ f32x2 pk_mul(f32x2 a, f32x2 b) {
  f32x2 d; asm("v_pk_mul_f32 %0, %1, %2" : "=v"(d) : "v"(a), "v"(b)); return d;
}
__device__ __forceinline__ f32x2 pk_fma(f32x2 a, f32x2 b, f32x2 c) {
  f32x2 d; asm("v_pk_fma_f32 %0, %1, %2, %3" : "=v"(d) : "v"(a), "v"(b), "v"(c)); return d;
}

// ---------------------------------------------------------------------------
// prep: x cast to bf16 ([0,512)) + wq/wk/wv transpose-cast ([512,2048)) +
// wo transpose-cast ([2048,3072)).  wT[n][k] = bf16(w[k][n]), stride 1024.
// ---------------------------------------------------------------------------
__global__ __launch_bounds__(256) void prep_kernel(const float* __restrict__ x,
                                                   const float* __restrict__ wq,
                                                   const float* __restrict__ wk,
                                                   const float* __restrict__ wv,
                                                   const float* __restrict__ wo,
                                                   u16* __restrict__ xb,
                                                   u16* __restrict__ wT,
                                                   u16* __restrict__ woT) {
  int bx = blockIdx.x;
  if (bx < 512) {
    const size_t base = (size_t)bx * 8192;
#pragma unroll
    for (int j = 0; j < 4; ++j) {
      size_t e = base + j * 2048 + threadIdx.x * 8;
      float4 f0 = *(const float4*)(x + e);
      float4 f1 = *(const float4*)(x + e + 4);
      uint4 u;
      u.x = cvtpk(f0.x, f0.y); u.y = cvtpk(f0.z, f0.w);
      u.z = cvtpk(f1.x, f1.y); u.w = cvtpk(f1.z, f1.w);
      *(uint4*)(xb + e) = u;
    }
    return;
  }
  bx -= 512;
  __shared__ float t[32][33];
  const float* src; u16* dst; int N, ntm, nts;
  if (bx < 1024)      { src = wq; dst = wT;                 N = 1024; ntm = 31; nts = 5; }
  else if (bx < 1280) { bx -= 1024; src = wk; dst = wT + (1024 << 10); N = 256; ntm = 7; nts = 3; }
  else if (bx < 1536) { bx -= 1280; src = wv; dst = wT + (1280 << 10); N = 256; ntm = 7; nts = 3; }
  else                { bx -= 1536; src = wo; dst = woT;    N = 1024; ntm = 31; nts = 5; }
  const int n0 = (bx & ntm) << 5, k0 = (bx >> nts) << 5;
  const int xx = threadIdx.x & 31, y = threadIdx.x >> 5;
#pragma unroll
  for (int i = 0; i < 4; ++i) {
    int r = y + (i << 3);
    t[r][xx] = src[(size_t)(k0 + r) * N + n0 + xx];
  }
  __syncthreads();
#pragma unroll
  for (int i = 0; i < 4; ++i) {
    int r = y + (i << 3);
    dst[(size_t)(n0 + r) * 1024 + k0 + xx] = f2bf(t[xx][r]);
  }
}

// ---------------------------------------------------------------------------
// QKV GEMM with fused RMSNorm+RoPE+layout epilogue (unchanged from r5).
// ---------------------------------------------------------------------------
__global__ __launch_bounds__(256, 2) void qkvgemm_kernel(const u16* __restrict__ xb,
                                                         const u16* __restrict__ wT,
                                                         u16* __restrict__ Qbf,
                                                         u16* __restrict__ Kbf,
                                                         u16* __restrict__ Vt) {
  __shared__ uint4 SM[4][512];
  const int tid = threadIdx.x;
  const int w = tid >> 6, l = tid & 63;
  const int wr = w >> 1, wc = w & 1;
  int wg = ((int)blockIdx.x & 7) * 48 + ((int)blockIdx.x >> 3);
  const int mt = wg / 12, nb = wg - mt * 12;
  const int m0 = mt << 7;

  f32x4 acc[4][4];
#pragma unroll
  for (int m = 0; m < 4; ++m)
#pragma unroll
    for (int n = 0; n < 4; ++n)
#pragma unroll
      for (int j = 0; j < 4; ++j) acc[m][n][j] = 0.f;

  auto stage = [&](int buf, int k0) {
    const u16* Ab = xb + (size_t)m0 * 1024 + k0;
#pragma unroll
    for (int r = 0; r < 2; ++r) {
      int i = (w << 1) + r;
      int row = (i << 4) + (l >> 2);
      const u16* g = Ab + (size_t)row * 1024 + ((l & 3) << 3);
      __builtin_amdgcn_global_load_lds((const AS1 void*)g,
          (AS3 void*)((char*)SM + (buf << 13) + (i << 10)), 16, 0, 0);
    }
    const u16* Bb = wT + (size_t)(nb << 7) * 1024 + k0;
#pragma unroll
    for (int r = 0; r < 2; ++r) {
      int i = (w << 1) + r;
      int row = (i << 4) + (l >> 2);
      const u16* g = Bb + (size_t)row * 1024 + ((l & 3) << 3);
      __builtin_amdgcn_global_load_lds((const AS1 void*)g,
          (AS3 void*)((char*)SM + ((2 + buf) << 13) + (i << 10)), 16, 0, 0);
    }
  };

  stage(0, 0);
#pragma unroll 1
  for (int kt = 0; kt < 32; ++kt) {
    __syncthreads();
    if (kt + 1 < 32) stage((kt + 1) & 1, (kt + 1) << 5);
    const char* Ab = (const char*)SM + ((kt & 1) << 13);
    const char* Bb = (const char*)SM + ((2 + (kt & 1)) << 13);
    short8 af[4], bf[4];
#pragma unroll
    for (int m = 0; m < 4; ++m)
      af[m] = *(const short8*)(Ab + ((wr * 64 + m * 16 + (l & 15)) << 6) + ((l >> 4) << 4));
#pragma unroll
    for (int n = 0; n < 4; ++n)
      bf[n] = *(const short8*)(Bb + ((wc * 64 + n * 16 + (l & 15)) << 6) + ((l >> 4) << 4));
#pragma unroll
    for (int m = 0; m < 4; ++m)
#pragma unroll
      for (int n = 0; n < 4; ++n)
        acc[m][n] = __builtin_amdgcn_mfma_f32_16x16x32_bf16(af[m], bf[n], acc[m][n], 0, 0, 0);
  }

  __syncthreads();
  const int b = m0 >> 11;
  const int pos0 = (m0 & 2047) + wr * 64;
  const int lg = l >> 4, lc = l & 15;
  u16* lds = (u16*)((char*)SM + (w << 13));

  if (nb < 10) {
    float rs[4][4];
#pragma unroll
    for (int m = 0; m < 4; ++m)
#pragma unroll
      for (int j = 0; j < 4; ++j) {
        float ssq = 0.f;
#pragma unroll
        for (int n = 0; n < 4; ++n) ssq = fmaf(acc[m][n][j], acc[m][n][j], ssq);
        ssq += __shfl_xor(ssq, 1); ssq += __shfl_xor(ssq, 2);
        ssq += __shfl_xor(ssq, 4); ssq += __shfl_xor(ssq, 8);
        rs[m][j] = rsqrtf(ssq * (1.f / 64.f) + 1e-5f);
      }
    const float osc = (nb < 8) ? 0.0025f : 1.0f;
    const float invf0 = powf(10000.0f, (float)lc * (-1.f / 32.f));
    const float invf1 = powf(10000.0f, (float)(lc + 16) * (-1.f / 32.f));
#pragma unroll
    for (int m = 0; m < 4; ++m) {
#pragma unroll
      for (int j = 0; j < 4; ++j) {
        const int row = m * 16 + lg * 4 + j;
        const float pos = (float)(pos0 + row);
        float s0, c0, s1, c1;
        sincosf(pos * invf0, &s0, &c0);
        sincosf(pos * invf1, &s1, &c1);
        const float r_ = rs[m][j];
        float x0 = acc[m][0][j] * r_, x1 = acc[m][1][j] * r_;
        float x2 = acc[m][2][j] * r_, x3 = acc[m][3][j] * r_;
        u16 o0 = f2bf((x0 * c0 - x2 * s0) * osc);
        u16 o1 = f2bf((x1 * c1 - x3 * s1) * osc);
        u16 o2 = f2bf((x2 * c0 + x0 * s0) * osc);
        u16 o3 = f2bf((x3 * c1 + x1 * s1) * osc);
        const int rb = row << 6, xr = (row & 7) << 3;
        lds[rb + (lc ^ xr)] = o0;
        lds[rb + ((16 + lc) ^ xr)] = o1;
        lds[rb + ((32 + lc) ^ xr)] = o2;
        lds[rb + ((48 + lc) ^ xr)] = o3;
      }
    }
  } else {
#pragma unroll
    for (int m = 0; m < 4; ++m)
#pragma unroll
      for (int n = 0; n < 4; ++n) {
        const int d = n * 16 + lc;
        const int tok = m * 16 + lg * 4;
        uint2 u;
        u.x = cvtpk(acc[m][n][0], acc[m][n][1]);
        u.y = cvtpk(acc[m][n][2], acc[m][n][3]);
        *(uint2*)(lds + (d << 6) + (tok ^ ((d & 7) << 3))) = u;
      }
  }
  __syncthreads();

  u16* gp; int rstride;
  if (nb < 8)       { gp = Qbf + ((size_t)((b * 16 + nb * 2 + wc) * 2048 + pos0) << 6); rstride = 64; }
  else if (nb < 10) { gp = Kbf + ((size_t)((b * 4 + (nb - 8) * 2 + wc) * 2048 + pos0) << 6); rstride = 64; }
  else              { gp = Vt + (((size_t)((b * 4 + (nb - 10) * 2 + wc) * 64)) << 11) + pos0; rstride = 2048; }
#pragma unroll
  for (int ic = 0; ic < 8; ++ic) {
    const int c = (ic << 6) + l;
    const int row = c >> 3, col8 = (c & 7) << 3;
    uint4 v = *(const uint4*)(lds + (row << 6) + (col8 ^ ((row & 7) << 3)));
    *(uint4*)(gp + (size_t)row * rstride + col8) = v;
  }
}

// ---------------------------------------------------------------------------
// Output projection (unchanged from r5).
// ---------------------------------------------------------------------------
__global__ __launch_bounds__(256, 2) void gemm_kernel(const u16* __restrict__ A,
                                                      const u16* __restrict__ BT,
                                                      float* __restrict__ C) {
  __shared__ uint4 SM[4][512];
  const int tid = threadIdx.x;
  const int w = tid >> 6, l = tid & 63;
  const int wr = w >> 1, wc = w & 1;
  int wg = ((int)blockIdx.x & 7) * 32 + ((int)blockIdx.x >> 3);
  const int m0 = (wg >> 3) << 7, n0 = (wg & 7) << 7;

  f32x4 acc[4][4];
#pragma unroll
  for (int m = 0; m < 4; ++m)
#pragma unroll
    for (int n = 0; n < 4; ++n)
#pragma unroll
      for (int j = 0; j < 4; ++j) acc[m][n][j] = 0.f;

  auto stage = [&](int buf, int k0) {
    const u16* Ab = A + (size_t)m0 * 1024 + k0;
#pragma unroll
    for (int r = 0; r < 2; ++r) {
      int i = (w << 1) + r;
      int row = (i << 4) + (l >> 2);
      const u16* g = Ab + (size_t)row * 1024 + ((l & 3) << 3);
      __builtin_amdgcn_global_load_lds((const AS1 void*)g,
          (AS3 void*)((char*)SM + (buf << 13) + (i << 10)), 16, 0, 0);
    }
    const u16* Bb = BT + (size_t)n0 * 1024 + k0;
#pragma unroll
    for (int r = 0; r < 2; ++r) {
      int i = (w << 1) + r;
      int row = (i << 4) + (l >> 2);
      const u16* g = Bb + (size_t)row * 1024 + ((l & 3) << 3);
      __builtin_amdgcn_global_load_lds((const AS1 void*)g,
          (AS3 void*)((char*)SM + ((2 + buf) << 13) + (i << 10)), 16, 0, 0);
    }
  };

  stage(0, 0);
#pragma unroll 1
  for (int kt = 0; kt < 32; ++kt) {
    __syncthreads();
    if (kt + 1 < 32) stage((kt + 1) & 1, (kt + 1) << 5);
    const char* Ab = (const char*)SM + ((kt & 1) << 13);
    const char* Bb = (const char*)SM + ((2 + (kt & 1)) << 13);
    short8 af[4], bf[4];
#pragma unroll
    for (int m = 0; m < 4; ++m)
      af[m] = *(const short8*)(Ab + ((wr * 64 + m * 16 + (l & 15)) << 6) + ((l >> 4) << 4));
#pragma unroll
    for (int n = 0; n < 4; ++n)
      bf[n] = *(const short8*)(Bb + ((wc * 64 + n * 16 + (l & 15)) << 6) + ((l >> 4) << 4));
#pragma unroll
    for (int m = 0; m < 4; ++m)
#pragma unroll
      for (int n = 0; n < 4; ++n)
        acc[m][n] = __builtin_amdgcn_mfma_f32_16x16x32_bf16(af[m], bf[n], acc[m][n], 0, 0, 0);
  }

#pragma unroll
  for (int m = 0; m < 4; ++m) {
    int row0 = m0 + wr * 64 + m * 16 + ((l >> 4) << 2);
#pragma unroll
    for (int n = 0; n < 4; ++n) {
      int col = n0 + wc * 64 + n * 16 + (l & 15);
#pragma unroll
      for (int j = 0; j < 4; ++j)
        C[(size_t)(row0 + j) * 1024 + col] = acc[m][n][j];
    }
  }
}

// ---------------------------------------------------------------------------
// Flash attention, GQA-shared: block = (b, hkv, 32-row q-tile), 4 waves = the
// 4 q-heads of the group sharing one K/V staging (staging VALU /4).  512
// blocks x 256 thr -> 2 blocks/CU (8 waves/CU).  blockIdx&7 = (b,hkv) so each
// XCD's L2 serves one kv-head.  Fixed-max softmax (p = exp(sc-8)), poly-tanh
// softcap with packed v_pk f32 ops, diagonal tile computes only its live half.
// ---------------------------------------------------------------------------
__device__ __forceinline__ short8 rdfrag(const uint4* lds, int row, int cb) {
  int byte = ((row << 7) + cb) ^ ((row & 7) << 4);
  return *(const short8*)((const char*)lds + byte);
}

__global__ __launch_bounds__(256, 2) void attn_kernel(const u16* __restrict__ Qbf,
                                                      const u16* __restrict__ Kbf,
                                                      const u16* __restrict__ Vt,
                                                      u16* __restrict__ ybf) {
  __shared__ uint4 KV[4][512];         // K0 V0 K1 V1, 64x64 bf16, XOR-swizzled
  const int tid = threadIdx.x;
  const int g = blockIdx.x & 7;        // b*4 + hkv  (constant per XCD)
  const int j = 63 - (blockIdx.x >> 3);// 32-row q-tile, heavy first
  const int b = g >> 2, hkv = g & 3;
  const int w = tid >> 6, l = tid & 63;
  const int ql = l & 31, myh = l >> 5;
  const int h = hkv * 4 + w;           // wave = one q-head of the group
  const int q0 = j << 5;
  const int qg = q0 + ql;

  const u16* Kg = Kbf + (((size_t)g) << 11) * 64;
  const u16* Vg = Vt + (((size_t)g) << 6) * 2048;

  short8 bq[4];
  {
    const u16* Qg = Qbf + ((size_t)((b * 16 + h) * 2048 + qg)) * 64 + myh * 8;
    bq[0] = *(const short8*)(Qg);
    bq[1] = *(const short8*)(Qg + 16);
    bq[2] = *(const short8*)(Qg + 32);
    bq[3] = *(const short8*)(Qg + 48);
  }

  f32x16 o0, o1;
#pragma unroll
  for (int i = 0; i < 16; ++i) { o0[i] = 0.f; o1[i] = 0.f; }
  float l_run = 0.f;

  const int KT = (j >> 1) + 1;

  auto stage = [&](int buf, int kt) {
    const u16* gk = Kg + ((size_t)(kt << 6)) * 64;
    const u16* gv = Vg + (kt << 6);
#pragma unroll
    for (int i = 0; i < 2; ++i) {
      int c = tid + (i << 8);            // 0..511 16B chunks
      int row = c >> 3, off = c & 7;
      uint4 kk4 = *(const uint4*)(gk + row * 64 + (off << 3));
      uint4 vv4 = *(const uint4*)(gv + (size_t)row * 2048 + (off << 3));
      int byte = ((row << 7) + (off << 4)) ^ ((row & 7) << 4);
      *(uint4*)((char*)KV[buf << 1] + byte) = kk4;
      *(uint4*)((char*)KV[(buf << 1) + 1] + byte) = vv4;
    }
  };

  stage(0, 0);

  const float PC2 = -0.33333333f;         // -1/3
  const float SC1 = 72.13475204444817f;   // 50*log2(e)
  const float SC0 = -11.541560327111708f; // -8*log2(e)
  const f32x2 PC2v = {PC2, PC2};
  const f32x2 SC1v = {SC1, SC1};
  const f32x2 SC0v = {SC0, SC0};
  const f32x2 ONEv = {1.0f, 1.0f};

#pragma unroll 1
  for (int kt = 0; kt < KT; ++kt) {
    const int buf = kt & 1;
    __syncthreads();
    if (kt + 1 < KT) stage(buf ^ 1, kt + 1);
    const bool last = (kt == KT - 1);
    const bool havehi = !last || (j & 1);  // hi k-half live?
    const uint4* Kl = KV[buf << 1];
    const uint4* Vl = KV[(buf << 1) + 1];

    f32x16 s0, s1;
#pragma unroll
    for (int i = 0; i < 16; ++i) { s0[i] = 0.f; s1[i] = 0.f; }
    __builtin_amdgcn_s_setprio(1);
#pragma unroll
    for (int c = 0; c < 4; ++c) {
      short8 ak = rdfrag(Kl, ql, (c << 5) + (myh << 4));
      s0 = __builtin_amdgcn_mfma_f32_32x32x16_bf16(ak, bq[c], s0, 0, 0, 0);
    }
    if (havehi) {
#pragma unroll
      for (int c = 0; c < 4; ++c) {
        short8 ak = rdfrag(Kl, 32 + ql, (c << 5) + (myh << 4));
        s1 = __builtin_amdgcn_mfma_f32_32x32x16_bf16(ak, bq[c], s1, 0, 0, 0);
      }
    }
    __builtin_amdgcn_s_setprio(0);

    float lsum = 0.f;
    auto cap_full = [&](f32x16& s) {       // packed poly, no mask
#pragma unroll
      for (int p = 0; p < 8; ++p) {
        f32x2 z; z.x = s[2 * p]; z.y = s[2 * p + 1];
        f32x2 z2 = pk_mul(z, z);
        f32x2 zc = pk_fma(z2, PC2v, ONEv);
        f32x2 zs = pk_mul(z, SC1v);
        f32x2 ar = pk_fma(zs, zc, SC0v);
        float p0 = exp2fast(ar.x);
        float p1 = exp2fast(ar.y);
        s[2 * p] = p0; s[2 * p + 1] = p1;
        lsum += p0; lsum += p1;
      }
    };
    auto cap_diag = [&](f32x16& s) {       // half whose k-base == q0
#pragma unroll
      for (int i = 0; i < 16; ++i) {
        int kl = (i & 3) + ((i >> 2) << 3) + (myh << 2);
        float z = s[i];
        float zc = fmaf(z * z, PC2, 1.0f);
        float p = exp2fast(fmaf(z * zc, SC1, SC0));
        p = (kl <= ql) ? p : 0.f;
        s[i] = p; lsum += p;
      }
    };
    if (!last)       { cap_full(s0); cap_full(s1); }
    else if (j & 1)  { cap_full(s0); cap_diag(s1); }
    else             { cap_diag(s0); }
    l_run += lsum;

    short8 pa[4];
    auto mkpa = [&](const f32x16& P, int c0) {
#pragma unroll
      for (int ci = 0; ci < 2; ++ci) {
        const int rb = ci << 3;
        u32 A = cvtpk(P[rb + 0], P[rb + 1]);
        u32 Cw = cvtpk(P[rb + 2], P[rb + 3]);
        u32 B = cvtpk(P[rb + 4], P[rb + 5]);
        u32 D = cvtpk(P[rb + 6], P[rb + 7]);
        plswap(A, B); plswap(Cw, D);
        union { u32 u[4]; short8 s; } pw_;
        pw_.u[0] = A; pw_.u[1] = Cw; pw_.u[2] = B; pw_.u[3] = D;
        pa[c0 + ci] = pw_.s;
      }
    };
    mkpa(s0, 0);
    if (havehi) mkpa(s1, 2);

    __builtin_amdgcn_s_setprio(1);
#pragma unroll
    for (int c = 0; c < 2; ++c) {
      short8 av = rdfrag(Vl, ql, (c << 5) + (myh << 4));
      o0 = __builtin_amdgcn_mfma_f32_32x32x16_bf16(av, pa[c], o0, 0, 0, 0);
      short8 av1 = rdfrag(Vl, 32 + ql, (c << 5) + (myh << 4));
      o1 = __builtin_amdgcn_mfma_f32_32x32x16_bf16(av1, pa[c], o1, 0, 0, 0);
    }
    if (havehi) {
#pragma unroll
      for (int c = 2; c < 4; ++c) {
        short8 av = rdfrag(Vl, ql, (c << 5) + (myh << 4));
        o0 = __builtin_amdgcn_mfma_f32_32x32x16_bf16(av, pa[c], o0, 0, 0, 0);
        short8 av1 = rdfrag(Vl, 32 + ql, (c << 5) + (myh << 4));
        o1 = __builtin_amdgcn_mfma_f32_32x32x16_bf16(av1, pa[c], o1, 0, 0, 0);
      }
    }
    __builtin_amdgcn_s_setprio(0);
  }

  float lr = l_run + __shfl_xor(l_run, 32);
  float rl = rcpfast(lr);
  u16* yr = ybf + ((size_t)(b * 2048 + qg)) * 1024 + h * 64;
#pragma unroll
  for (int i = 0; i < 16; i += 2) {
    int dof = (i & 3) + ((i >> 2) << 3) + (myh << 2);
    *(u32*)(yr + dof) = cvtpk(o0[i] * rl, o0[i + 1] * rl);
    *(u32*)(yr + 32 + dof) = cvtpk(o1[i] * rl, o1[i + 1] * rl);
  }
}

// ---------------------------------------------------------------------------
extern "C" void kernel_launch(void* const* d_in, const int* in_sizes, int n_in,
                              void* d_out, int out_size, void* d_ws, size_t ws_size,
                              hipStream_t stream) {
  (void)in_sizes; (void)n_in; (void)out_size; (void)ws_size;
  const float* x  = (const float*)d_in[0];
  const float* wq = (const float*)d_in[1];
  const float* wk = (const float*)d_in[2];
  const float* wv = (const float*)d_in[3];
  const float* wo = (const float*)d_in[4];
  float* out = (float*)d_out;

  char* ws = (char*)d_ws;                // 33 MiB total, no aliasing
  u16* xb  = (u16*)ws;                   // [0, 8M)
  u16* ybf = (u16*)(ws + (8u << 20));    // [8, 16M)
  u16* woT = (u16*)(ws + (16u << 20));   // [16, 18M)
  u16* wT  = (u16*)(ws + (18u << 20));   // [18, 21M)
  u16* Qbf = (u16*)(ws + (21u << 20));   // [21, 29M)
  u16* Kbf = (u16*)(ws + (29u << 20));   // [29, 31M)
  u16* Vt  = (u16*)(ws + (31u << 20));   // [31, 33M)

  prep_kernel<<<dim3(3072), 256, 0, stream>>>(x, wq, wk, wv, wo, xb, wT, woT);
  qkvgemm_kernel<<<dim3(384), 256, 0, stream>>>(xb, wT, Qbf, Kbf, Vt);
  attn_kernel<<<dim3(512), 256, 0, stream>>>(Qbf, Kbf, Vt, ybf);
  gemm_kernel<<<dim3(256), 256, 0, stream>>>(ybf, woT, out);
}